// Round 11
// baseline (6628.647 us; speedup 1.0000x reference)
//
#include <hip/hip_runtime.h>
#include <hip/hip_bf16.h>

#define N_NODES 200000
#define N_EDGES 400000
#define N_GRAPHS 4096
#define HDIM 300
#define H2DIM 600
#define NLAYERS 5

typedef __hip_bfloat16 bf16;
typedef __attribute__((ext_vector_type(4))) short s16x4;
typedef __attribute__((ext_vector_type(8))) short s16x8;
typedef __attribute__((ext_vector_type(4))) float f32x4v;

__device__ inline short f2bf(float f) {
    __hip_bfloat16 b = __float2bfloat16(f);
    return *(short*)&b;
}
__device__ inline float bf2f(short s) {
    __hip_bfloat16 b = *(__hip_bfloat16*)&s;
    return __bfloat162float(b);
}

// async global->LDS DMA, 16B per lane; LDS dest = wave-uniform base + lane*16
__device__ inline void gload_lds16(const short* g, short* l) {
    __builtin_amdgcn_global_load_lds(
        (const __attribute__((address_space(1))) unsigned int*)g,
        (__attribute__((address_space(3))) unsigned int*)l,
        16, 0, 0);
}

// ---------------------------------------------------------------------------
// Diagnostic (ws too small): report ws_size MB via d_out
// ---------------------------------------------------------------------------
__global__ void diag_kernel(float* __restrict__ out, int n, float val) {
    int i = blockIdx.x * blockDim.x + threadIdx.x;
    if (i < n) out[i] = val;
}

// ---------------------------------------------------------------------------
// Edge sort by dst: histogram -> scan -> scatter.
// ---------------------------------------------------------------------------
__global__ void hist_kernel(const int* __restrict__ edge_index, int* __restrict__ offs) {
    int e = blockIdx.x * blockDim.x + threadIdx.x;
    if (e >= N_EDGES) return;
    atomicAdd(&offs[edge_index[N_EDGES + e]], 1);
}

#define SCAN_N 200001
__global__ void scan1_kernel(int* __restrict__ offs, int* __restrict__ bsum) {
    __shared__ int ls[256];
    int tid = threadIdx.x;
    int base = blockIdx.x * 1024 + tid * 4;
    int v[4];
#pragma unroll
    for (int j = 0; j < 4; j++) v[j] = (base + j < SCAN_N) ? offs[base + j] : 0;
    int t = v[0] + v[1] + v[2] + v[3];
    ls[tid] = t;
    __syncthreads();
    for (int off = 1; off < 256; off <<= 1) {
        int y = (tid >= off) ? ls[tid - off] : 0;
        __syncthreads();
        ls[tid] += y;
        __syncthreads();
    }
    int ex = ls[tid] - t;
#pragma unroll
    for (int j = 0; j < 4; j++) {
        if (base + j < SCAN_N) offs[base + j] = ex;
        ex += v[j];
    }
    if (tid == 255) bsum[blockIdx.x] = ls[255];
}

__global__ void scan2_kernel(int* __restrict__ bsum, int nb) {
    __shared__ int ls[256];
    int tid = threadIdx.x;
    int v = (tid < nb) ? bsum[tid] : 0;
    ls[tid] = v;
    __syncthreads();
    for (int off = 1; off < 256; off <<= 1) {
        int y = (tid >= off) ? ls[tid - off] : 0;
        __syncthreads();
        ls[tid] += y;
        __syncthreads();
    }
    if (tid < nb) bsum[tid] = ls[tid] - v;
}

__global__ void scan3_kernel(int* __restrict__ offs, const int* __restrict__ bsum) {
    int i = blockIdx.x * blockDim.x + threadIdx.x;
    if (i >= SCAN_N) return;
    offs[i] += bsum[i >> 10];
}

__global__ void scatter_kernel(const int* __restrict__ edge_index,
                               const int* __restrict__ edge_attr,
                               int* __restrict__ offs,
                               int* __restrict__ sidx) {
    int e = blockIdx.x * blockDim.x + threadIdx.x;
    if (e >= N_EDGES) return;
    int src = edge_index[e];
    int dst = edge_index[N_EDGES + e];
    int combo = edge_attr[e * 3 + 0] | (edge_attr[e * 3 + 1] << 4) | (edge_attr[e * 3 + 2] << 8);
    int pos = atomicAdd(&offs[dst], 1);
    sidx[pos] = src | (combo << 18);
}

// ---------------------------------------------------------------------------
// Bond-embedding table: etab[combo][c] (stride 304), bf16
// ---------------------------------------------------------------------------
__global__ void etab_kernel(const float* __restrict__ bond_l, short* __restrict__ etab) {
    int idx = blockIdx.x * blockDim.x + threadIdx.x;
    if (idx >= 4096 * 304) return;
    int combo = idx / 304;
    int c = idx - combo * 304;
    if (c >= HDIM) { etab[idx] = 0; return; }
    int a0 = combo & 15, a1 = (combo >> 4) & 15, a2 = combo >> 8;
    float v = bond_l[a0 * HDIM + c] + bond_l[16 * HDIM + a1 * HDIM + c]
            + bond_l[32 * HDIM + a2 * HDIM + c];
    etab[idx] = f2bf(v);
}

// ---------------------------------------------------------------------------
// Weight swizzle into MFMA B-fragment order.
// Wt1s: [l][nt(40)][kb(10)][lane(64)][8]; Wt2s: [l][nt(20)][kb(20)][lane(64)][8]
// ---------------------------------------------------------------------------
__global__ void prep_w_swz(const float* __restrict__ W1, const float* __restrict__ W2,
                           short* __restrict__ Wt1s, short* __restrict__ Wt2s) {
    int idx = blockIdx.x * blockDim.x + threadIdx.x;
    const int G1 = NLAYERS * 40 * 10 * 64;
    const int G2 = NLAYERS * 20 * 20 * 64;
    if (idx < G1) {
        int l = idx / (40 * 10 * 64);
        int r = idx - l * (40 * 10 * 64);
        int nt = r / (10 * 64);
        int r2 = r - nt * (10 * 64);
        int kb = r2 >> 6;
        int lane = r2 & 63;
        int n = nt * 16 + (lane & 15);
        int k0 = kb * 32 + (lane >> 4) * 8;
        s16x8 o;
#pragma unroll
        for (int j = 0; j < 8; j++) {
            int k = k0 + j;
            float v = (n < H2DIM && k < HDIM) ? W1[((size_t)l * HDIM + k) * H2DIM + n] : 0.f;
            o[j] = f2bf(v);
        }
        *(s16x8*)&Wt1s[(size_t)idx * 8] = o;
    } else if (idx < G1 + G2) {
        int t = idx - G1;
        int l = t / (20 * 20 * 64);
        int r = t - l * (20 * 20 * 64);
        int nt = r / (20 * 64);
        int r2 = r - nt * (20 * 64);
        int kb = r2 >> 6;
        int lane = r2 & 63;
        int n = nt * 16 + (lane & 15);
        int k0 = kb * 32 + (lane >> 4) * 8;
        s16x8 o;
#pragma unroll
        for (int j = 0; j < 8; j++) {
            int k = k0 + j;
            float v = (n < HDIM && k < H2DIM) ? W2[((size_t)l * H2DIM + k) * HDIM + n] : 0.f;
            o[j] = f2bf(v);
        }
        *(s16x8*)&Wt2s[(size_t)t * 8] = o;
    }
}

// ---------------------------------------------------------------------------
// AtomEncoder -> h bf16 (vectorized: one thread per 4 cols)
// ---------------------------------------------------------------------------
__global__ void atom_kernel(const int* __restrict__ x,
                            const float* __restrict__ atom_emb,
                            short* __restrict__ h) {
    int i = blockIdx.x * blockDim.x + threadIdx.x;
    if (i >= N_NODES * 75) return;
    int n = i / 75;
    int c = (i - n * 75) * 4;
    const int* xr = x + n * 9;
    float4 s = {0.f, 0.f, 0.f, 0.f};
#pragma unroll
    for (int f = 0; f < 9; f++) {
        float4 v = *(const float4*)&atom_emb[(size_t)(f * 120 + xr[f]) * HDIM + c];
        s.x += v.x; s.y += v.y; s.z += v.z; s.w += v.w;
    }
    s16x4 o = {f2bf(s.x), f2bf(s.y), f2bf(s.z), f2bf(s.w)};
    *(s16x4*)&h[(size_t)n * HDIM + c] = o;
}

// ---------------------------------------------------------------------------
// Aggregation kernel (unchanged from R6-R8)
// ---------------------------------------------------------------------------
__launch_bounds__(256)
__global__ void agg_kernel(const short* __restrict__ h_in,
                           short* __restrict__ z,
                           const int* __restrict__ offs,
                           const int* __restrict__ sidx,
                           const short* __restrict__ etab,
                           const float* __restrict__ eps, int l) {
    int tid = threadIdx.x;
    int q = tid >> 4;
    int l16 = tid & 15;
    int n = blockIdx.x * 16 + q;
    float e1 = 1.f + eps[l];
    int beg = (n == 0) ? 0 : offs[n - 1];
    int end = offs[n];

    float4 acc[5];
#pragma unroll
    for (int j = 0; j < 5; j++) acc[j] = (float4){0.f, 0.f, 0.f, 0.f};
    bool tail = l16 < 11;
    int ctail = 256 + l16 * 4;

    int e = beg;
    for (; e + 2 <= end; e += 2) {
        int pk0 = sidx[e];
        int pk1 = sidx[e + 1];
        const short* hr0 = h_in + (size_t)(pk0 & 0x3FFFF) * HDIM;
        const short* er0 = etab + (((unsigned)pk0) >> 18) * 304;
        const short* hr1 = h_in + (size_t)(pk1 & 0x3FFFF) * HDIM;
        const short* er1 = etab + (((unsigned)pk1) >> 18) * 304;
        s16x4 hv0[5], ev0[5], hv1[5], ev1[5];
#pragma unroll
        for (int rep = 0; rep < 4; rep++) {
            int c = rep * 64 + l16 * 4;
            hv0[rep] = *(const s16x4*)(hr0 + c);
            ev0[rep] = *(const s16x4*)(er0 + c);
            hv1[rep] = *(const s16x4*)(hr1 + c);
            ev1[rep] = *(const s16x4*)(er1 + c);
        }
        if (tail) {
            hv0[4] = *(const s16x4*)(hr0 + ctail);
            ev0[4] = *(const s16x4*)(er0 + ctail);
            hv1[4] = *(const s16x4*)(hr1 + ctail);
            ev1[4] = *(const s16x4*)(er1 + ctail);
        }
#pragma unroll
        for (int rep = 0; rep < 5; rep++) {
            if (rep == 4 && !tail) continue;
            acc[rep].x += fmaxf(0.f, bf2f(hv0[rep].x) + bf2f(ev0[rep].x))
                        + fmaxf(0.f, bf2f(hv1[rep].x) + bf2f(ev1[rep].x));
            acc[rep].y += fmaxf(0.f, bf2f(hv0[rep].y) + bf2f(ev0[rep].y))
                        + fmaxf(0.f, bf2f(hv1[rep].y) + bf2f(ev1[rep].y));
            acc[rep].z += fmaxf(0.f, bf2f(hv0[rep].z) + bf2f(ev0[rep].z))
                        + fmaxf(0.f, bf2f(hv1[rep].z) + bf2f(ev1[rep].z));
            acc[rep].w += fmaxf(0.f, bf2f(hv0[rep].w) + bf2f(ev0[rep].w))
                        + fmaxf(0.f, bf2f(hv1[rep].w) + bf2f(ev1[rep].w));
        }
    }
    if (e < end) {
        int pk0 = sidx[e];
        const short* hr0 = h_in + (size_t)(pk0 & 0x3FFFF) * HDIM;
        const short* er0 = etab + (((unsigned)pk0) >> 18) * 304;
        s16x4 hv0[5], ev0[5];
#pragma unroll
        for (int rep = 0; rep < 4; rep++) {
            int c = rep * 64 + l16 * 4;
            hv0[rep] = *(const s16x4*)(hr0 + c);
            ev0[rep] = *(const s16x4*)(er0 + c);
        }
        if (tail) {
            hv0[4] = *(const s16x4*)(hr0 + ctail);
            ev0[4] = *(const s16x4*)(er0 + ctail);
        }
#pragma unroll
        for (int rep = 0; rep < 5; rep++) {
            if (rep == 4 && !tail) continue;
            acc[rep].x += fmaxf(0.f, bf2f(hv0[rep].x) + bf2f(ev0[rep].x));
            acc[rep].y += fmaxf(0.f, bf2f(hv0[rep].y) + bf2f(ev0[rep].y));
            acc[rep].z += fmaxf(0.f, bf2f(hv0[rep].z) + bf2f(ev0[rep].z));
            acc[rep].w += fmaxf(0.f, bf2f(hv0[rep].w) + bf2f(ev0[rep].w));
        }
    }

    const short* hn = h_in + (size_t)n * HDIM;
    short* zr = z + (size_t)n * HDIM;
#pragma unroll
    for (int rep = 0; rep < 5; rep++) {
        if (rep == 4 && !tail) continue;
        int c = rep < 4 ? rep * 64 + l16 * 4 : ctail;
        s16x4 hv = *(const s16x4*)(hn + c);
        s16x4 o;
        o.x = f2bf(fmaf(e1, bf2f(hv.x), acc[rep].x));
        o.y = f2bf(fmaf(e1, bf2f(hv.y), acc[rep].y));
        o.z = f2bf(fmaf(e1, bf2f(hv.z), acc[rep].z));
        o.w = f2bf(fmaf(e1, bf2f(hv.w), acc[rep].w));
        *(s16x4*)(zr + c) = o;
    }
}

// ---------------------------------------------------------------------------
// MLP kernel v6: R8's 2-barrier structure, but NO Zs LDS tile — A-fragments
// read directly from global z (all 4 waves read the same rows -> L1-served;
// k>=300 over-read multiplies zero-padded W rows, harmless). LDS drops to
// Wbuf 20480B + Ys 17408B, h-tile epilogue reuses 38400B total
// -> 4 blocks/CU (was 2): barrier stalls of one block now hidden by 3 others.
// ---------------------------------------------------------------------------
#define WBUF_OFF 0
#define WBUF_SHORTS (20 * 64 * 8)              /* 10240 shorts = 20480 B */
#define YS_OFF WBUF_SHORTS                     /* 10240 */
#define YST 136
#define LDS_SHORTS (64 * HDIM)                 /* 19200 shorts = 38400 B */

__launch_bounds__(256, 4)
__global__ void mlp_kernel(const short* __restrict__ zin,
                           short* __restrict__ hout,
                           const short* __restrict__ Wt1,
                           const short* __restrict__ Wt2,
                           const float* __restrict__ b1l,
                           const float* __restrict__ gammal,
                           const float* __restrict__ betal,
                           const float* __restrict__ meanl,
                           const float* __restrict__ varl,
                           const float* __restrict__ b2l) {
    __shared__ short lds[LDS_SHORTS];
    int tid = threadIdx.x;
    int wng = tid >> 6;          // wave = N-group 0..3
    int lane = tid & 63;
    int quad = lane >> 4;
    int l16 = lane & 15;
    int row0 = blockIdx.x * 64;

    f32x4v acc2[4][5];
#pragma unroll
    for (int rt = 0; rt < 4; rt++)
#pragma unroll
        for (int ct = 0; ct < 5; ct++) acc2[rt][ct] = (f32x4v){0.f, 0.f, 0.f, 0.f};

    for (int cc = 0; cc < 5; cc++) {
        // ---------- stage 1: C1[64 x 128] = Z @ W1[:, cc*128..+127] ----------
        f32x4v acc1[4][2];
#pragma unroll
        for (int rt = 0; rt < 4; rt++)
#pragma unroll
            for (int ct = 0; ct < 2; ct++) acc1[rt][ct] = (f32x4v){0.f, 0.f, 0.f, 0.f};

        for (int kbp = 0; kbp < 5; kbp++) {
            __syncthreads();   // prior Wbuf consumers done
            // DMA 16 KB of W1: 16 chunks of 1KB, 4 per wave
#pragma unroll
            for (int j = 0; j < 4; j++) {
                int c = j * 4 + wng;
                int nt_ = c >> 1, kb2 = c & 1;
                const short* src = Wt1 +
                    ((size_t)(((cc * 8 + nt_) * 10 + kbp * 2 + kb2) * 64) + lane) * 8;
                gload_lds16(src, &lds[WBUF_OFF + c * 512]);
            }
            __syncthreads();
#pragma unroll
            for (int kb2 = 0; kb2 < 2; kb2++) {
                int ks = (kbp * 2 + kb2) * 32 + quad * 8;
                s16x8 a[4];
#pragma unroll
                for (int rt = 0; rt < 4; rt++)
                    a[rt] = *(const s16x8*)&zin[(size_t)(row0 + rt * 16 + l16) * HDIM + ks];
#pragma unroll
                for (int ct = 0; ct < 2; ct++) {
                    int c = (wng * 2 + ct) * 2 + kb2;
                    s16x8 b = *(const s16x8*)&lds[WBUF_OFF + c * 512 + lane * 8];
#pragma unroll
                    for (int rt = 0; rt < 4; rt++)
                        acc1[rt][ct] = __builtin_amdgcn_mfma_f32_16x16x32_bf16(a[rt], b, acc1[rt][ct], 0, 0, 0);
                }
            }
        }
        // ---------- epilogue: BN + ReLU -> Ys ----------
#pragma unroll
        for (int ct = 0; ct < 2; ct++) {
            int kc = wng * 32 + ct * 16 + l16;
            int col = cc * 128 + kc;
            bool valid = col < H2DIM;
            float s = 0.f, sh = 0.f;
            if (valid) {
                s = gammal[col] * rsqrtf(varl[col] + 1e-5f);
                sh = betal[col] + (b1l[col] - meanl[col]) * s;
            }
#pragma unroll
            for (int rt = 0; rt < 4; rt++)
#pragma unroll
                for (int rr = 0; rr < 4; rr++) {
                    float v = valid ? fmaxf(0.f, fmaf(acc1[rt][ct][rr], s, sh)) : 0.f;
                    lds[YS_OFF + (rt * 16 + quad * 4 + rr) * YST + kc] = f2bf(v);
                }
        }
        // ---------- stage 2: acc2 += Ys @ W2[cc*128.., :] ----------
#pragma unroll
        for (int kbl = 0; kbl < 4; kbl++) {
            __syncthreads();   // Ys written + Wbuf consumers done
            // DMA 20 KB of W2: 20 chunks of 1KB, 5 per wave
#pragma unroll
            for (int j = 0; j < 5; j++) {
                int c = j * 4 + wng;
                const short* src = Wt2 +
                    ((size_t)((c * 20 + cc * 4 + kbl) * 64) + lane) * 8;
                gload_lds16(src, &lds[WBUF_OFF + c * 512]);
            }
            __syncthreads();
            int ks = kbl * 32 + quad * 8;
            s16x8 a[4];
#pragma unroll
            for (int rt = 0; rt < 4; rt++)
                a[rt] = *(const s16x8*)&lds[YS_OFF + (rt * 16 + l16) * YST + ks];
#pragma unroll
            for (int ct = 0; ct < 5; ct++) {
                int c = wng * 5 + ct;
                s16x8 b = *(const s16x8*)&lds[WBUF_OFF + c * 512 + lane * 8];
#pragma unroll
                for (int rt = 0; rt < 4; rt++)
                    acc2[rt][ct] = __builtin_amdgcn_mfma_f32_16x16x32_bf16(a[rt], b, acc2[rt][ct], 0, 0, 0);
            }
        }
    }
    // ---------- epilogue: h-tile into LDS (stride 300, overlaps Wbuf+Ys:
    // barrier first), then coalesced contiguous copy-out ----------
    __syncthreads();
#pragma unroll
    for (int ct = 0; ct < 5; ct++) {
        int col = wng * 80 + ct * 16 + l16;
        if (col < HDIM) {
            float bb = b2l[col];
#pragma unroll
            for (int rt = 0; rt < 4; rt++)
#pragma unroll
                for (int rr = 0; rr < 4; rr++) {
                    int r = rt * 16 + quad * 4 + rr;
                    lds[r * HDIM + col] = f2bf(acc2[rt][ct][rr] + bb);
                }
        }
    }
    __syncthreads();
    for (int i = tid; i < 64 * 75; i += 256) {
        *(s16x4*)&hout[(size_t)row0 * HDIM + i * 4] = *(const s16x4*)&lds[i * 4];
    }
}

// ---------------------------------------------------------------------------
// Mean pool per graph (batch sorted) + classifier (vectorized)
// ---------------------------------------------------------------------------
__device__ int lower_bound_dev(const int* a, int n, int v) {
    int lo = 0, hi = n;
    while (lo < hi) {
        int mid = (lo + hi) >> 1;
        if (a[mid] < v) lo = mid + 1; else hi = mid;
    }
    return lo;
}

__global__ void pool_kernel(const short* __restrict__ h,
                            const int* __restrict__ batch,
                            const float* __restrict__ cls_W,
                            const float* __restrict__ cls_b,
                            float* __restrict__ out) {
    __shared__ int seg[2];
    __shared__ float r0s[256], r1s[256];
    int g = blockIdx.x;
    int t = threadIdx.x;
    if (t == 0) {
        seg[0] = lower_bound_dev(batch, N_NODES, g);
        seg[1] = lower_bound_dev(batch, N_NODES, g + 1);
    }
    __syncthreads();
    int s = seg[0], e = seg[1];
    float inv = 1.f / fmaxf((float)(e - s), 1.f);
    float p0 = 0.f, p1 = 0.f;
    if (t < 75) {
        int c = t * 4;
        float4 sum = {0.f, 0.f, 0.f, 0.f};
        for (int n = s; n < e; n++) {
            s16x4 v = *(const s16x4*)&h[(size_t)n * HDIM + c];
            sum.x += bf2f(v.x);
            sum.y += bf2f(v.y);
            sum.z += bf2f(v.z);
            sum.w += bf2f(v.w);
        }
        float4 gf = {sum.x * inv, sum.y * inv, sum.z * inv, sum.w * inv};
        *(float4*)&out[2 * N_GRAPHS + (size_t)g * HDIM + c] = gf;
        p0 = gf.x * cls_W[c * 2] + gf.y * cls_W[(c + 1) * 2]
           + gf.z * cls_W[(c + 2) * 2] + gf.w * cls_W[(c + 3) * 2];
        p1 = gf.x * cls_W[c * 2 + 1] + gf.y * cls_W[(c + 1) * 2 + 1]
           + gf.z * cls_W[(c + 2) * 2 + 1] + gf.w * cls_W[(c + 3) * 2 + 1];
    }
    r0s[t] = p0;
    r1s[t] = p1;
    __syncthreads();
    for (int st = 128; st > 0; st >>= 1) {
        if (t < st) { r0s[t] += r0s[t + st]; r1s[t] += r1s[t + st]; }
        __syncthreads();
    }
    if (t == 0) {
        out[g * 2 + 0] = r0s[0] + cls_b[0];
        out[g * 2 + 1] = r1s[0] + cls_b[1];
    }
}

// ---------------------------------------------------------------------------
extern "C" void kernel_launch(void* const* d_in, const int* in_sizes, int n_in,
                              void* d_out, int out_size, void* d_ws, size_t ws_size,
                              hipStream_t stream) {
    const int* x          = (const int*)d_in[0];
    const int* edge_index = (const int*)d_in[1];
    const int* edge_attr  = (const int*)d_in[2];
    const int* batch      = (const int*)d_in[3];
    const float* atom_emb = (const float*)d_in[4];
    const float* bond_emb = (const float*)d_in[5];
    const float* eps      = (const float*)d_in[6];
    const float* W1       = (const float*)d_in[7];
    const float* b1       = (const float*)d_in[8];
    const float* bn_gamma = (const float*)d_in[9];
    const float* bn_beta  = (const float*)d_in[10];
    const float* bn_mean  = (const float*)d_in[11];
    const float* bn_var   = (const float*)d_in[12];
    const float* W2       = (const float*)d_in[13];
    const float* b2       = (const float*)d_in[14];
    const float* cls_W    = (const float*)d_in[15];
    const float* cls_b    = (const float*)d_in[16];
    float* out = (float*)d_out;

    char* base = (char*)d_ws;
    const size_t OFF_HA   = 0;                       // 120,000,000
    const size_t OFF_HB   = 120000000;               // 120,000,000 (z / ping-pong)
    const size_t OFF_WT1  = 240000000;               //   2,048,000
    const size_t OFF_WT2  = 242048000;               //   2,048,000
    const size_t OFF_ETAB = 244096000;               //   2,490,368
    const size_t OFF_SIDX = 246586368;               //   1,600,000
    const size_t OFF_OFFS = 248186368;               //     800,016
    const size_t OFF_BSUM = 248986384;               //         784
    const size_t TOTAL    = 248987168;

    if (ws_size < TOTAL) {
        float mb = (float)(ws_size >> 20);
        diag_kernel<<<(out_size + 255) / 256, 256, 0, stream>>>(out, out_size, mb);
        return;
    }

    short* hA   = (short*)(base + OFF_HA);
    short* hB   = (short*)(base + OFF_HB);
    short* Wt1s = (short*)(base + OFF_WT1);
    short* Wt2s = (short*)(base + OFF_WT2);
    short* etab = (short*)(base + OFF_ETAB);
    int*   sidx = (int*)(base + OFF_SIDX);
    int*   offs = (int*)(base + OFF_OFFS);
    int*   bsum = (int*)(base + OFF_BSUM);

    // ---- edge sort by dst ----
    hipMemsetAsync(offs, 0, SCAN_N * sizeof(int), stream);
    hist_kernel<<<(N_EDGES + 255) / 256, 256, 0, stream>>>(edge_index, offs);
    scan1_kernel<<<196, 256, 0, stream>>>(offs, bsum);
    scan2_kernel<<<1, 256, 0, stream>>>(bsum, 196);
    scan3_kernel<<<(SCAN_N + 255) / 256, 256, 0, stream>>>(offs, bsum);
    scatter_kernel<<<(N_EDGES + 255) / 256, 256, 0, stream>>>(edge_index, edge_attr, offs, sidx);

    // ---- weight swizzle + atom encoder ----
    {
        int total = NLAYERS * 40 * 10 * 64 + NLAYERS * 20 * 20 * 64;
        prep_w_swz<<<(total + 255) / 256, 256, 0, stream>>>(W1, W2, Wt1s, Wt2s);
    }
    atom_kernel<<<(N_NODES * 75 + 255) / 256, 256, 0, stream>>>(x, atom_emb, hA);

    // ---- layers: agg hA->hB(z), mlp hB->hA ----
    for (int l = 0; l < NLAYERS; l++) {
        etab_kernel<<<(4096 * 304 + 255) / 256, 256, 0, stream>>>(
            bond_emb + (size_t)l * 3 * 16 * HDIM, etab);
        agg_kernel<<<N_NODES / 16, 256, 0, stream>>>(
            hA, hB, offs, sidx, etab, eps, l);
        mlp_kernel<<<N_NODES / 64, 256, 0, stream>>>(
            hB, hA,
            Wt1s + (size_t)l * 640 * 320, Wt2s + (size_t)l * 320 * 640,
            b1 + l * H2DIM, bn_gamma + l * H2DIM, bn_beta + l * H2DIM,
            bn_mean + l * H2DIM, bn_var + l * H2DIM, b2 + l * HDIM);
    }

    // ---- pool + classifier ----
    pool_kernel<<<N_GRAPHS, 256, 0, stream>>>(hA, batch, cls_W, cls_b, out);
}

// Round 12
// 4468.512 us; speedup vs baseline: 1.4834x; 1.4834x over previous
//
#include <hip/hip_runtime.h>
#include <hip/hip_bf16.h>

#define N_NODES 200000
#define N_EDGES 400000
#define N_GRAPHS 4096
#define HDIM 300
#define H2DIM 600
#define NLAYERS 5

typedef __hip_bfloat16 bf16;
typedef __attribute__((ext_vector_type(4))) short s16x4;
typedef __attribute__((ext_vector_type(8))) short s16x8;
typedef __attribute__((ext_vector_type(4))) float f32x4v;

__device__ inline short f2bf(float f) {
    __hip_bfloat16 b = __float2bfloat16(f);
    return *(short*)&b;
}
__device__ inline float bf2f(short s) {
    __hip_bfloat16 b = *(__hip_bfloat16*)&s;
    return __bfloat162float(b);
}

// async global->LDS DMA, 16B per lane; LDS dest = wave-uniform base + lane*16
__device__ inline void gload_lds16(const short* g, short* l) {
    __builtin_amdgcn_global_load_lds(
        (const __attribute__((address_space(1))) unsigned int*)g,
        (__attribute__((address_space(3))) unsigned int*)l,
        16, 0, 0);
}

// ---------------------------------------------------------------------------
// Diagnostic (ws too small): report ws_size MB via d_out
// ---------------------------------------------------------------------------
__global__ void diag_kernel(float* __restrict__ out, int n, float val) {
    int i = blockIdx.x * blockDim.x + threadIdx.x;
    if (i < n) out[i] = val;
}

// ---------------------------------------------------------------------------
// Edge sort by dst: histogram -> scan -> scatter.
// ---------------------------------------------------------------------------
__global__ void hist_kernel(const int* __restrict__ edge_index, int* __restrict__ offs) {
    int e = blockIdx.x * blockDim.x + threadIdx.x;
    if (e >= N_EDGES) return;
    atomicAdd(&offs[edge_index[N_EDGES + e]], 1);
}

#define SCAN_N 200001
__global__ void scan1_kernel(int* __restrict__ offs, int* __restrict__ bsum) {
    __shared__ int ls[256];
    int tid = threadIdx.x;
    int base = blockIdx.x * 1024 + tid * 4;
    int v[4];
#pragma unroll
    for (int j = 0; j < 4; j++) v[j] = (base + j < SCAN_N) ? offs[base + j] : 0;
    int t = v[0] + v[1] + v[2] + v[3];
    ls[tid] = t;
    __syncthreads();
    for (int off = 1; off < 256; off <<= 1) {
        int y = (tid >= off) ? ls[tid - off] : 0;
        __syncthreads();
        ls[tid] += y;
        __syncthreads();
    }
    int ex = ls[tid] - t;
#pragma unroll
    for (int j = 0; j < 4; j++) {
        if (base + j < SCAN_N) offs[base + j] = ex;
        ex += v[j];
    }
    if (tid == 255) bsum[blockIdx.x] = ls[255];
}

__global__ void scan2_kernel(int* __restrict__ bsum, int nb) {
    __shared__ int ls[256];
    int tid = threadIdx.x;
    int v = (tid < nb) ? bsum[tid] : 0;
    ls[tid] = v;
    __syncthreads();
    for (int off = 1; off < 256; off <<= 1) {
        int y = (tid >= off) ? ls[tid - off] : 0;
        __syncthreads();
        ls[tid] += y;
        __syncthreads();
    }
    if (tid < nb) bsum[tid] = ls[tid] - v;
}

__global__ void scan3_kernel(int* __restrict__ offs, const int* __restrict__ bsum) {
    int i = blockIdx.x * blockDim.x + threadIdx.x;
    if (i >= SCAN_N) return;
    offs[i] += bsum[i >> 10];
}

__global__ void scatter_kernel(const int* __restrict__ edge_index,
                               const int* __restrict__ edge_attr,
                               int* __restrict__ offs,
                               int* __restrict__ sidx) {
    int e = blockIdx.x * blockDim.x + threadIdx.x;
    if (e >= N_EDGES) return;
    int src = edge_index[e];
    int dst = edge_index[N_EDGES + e];
    int combo = edge_attr[e * 3 + 0] | (edge_attr[e * 3 + 1] << 4) | (edge_attr[e * 3 + 2] << 8);
    int pos = atomicAdd(&offs[dst], 1);
    sidx[pos] = src | (combo << 18);
}

// ---------------------------------------------------------------------------
// Bond-embedding table: etab[combo][c] (stride 304), bf16
// ---------------------------------------------------------------------------
__global__ void etab_kernel(const float* __restrict__ bond_l, short* __restrict__ etab) {
    int idx = blockIdx.x * blockDim.x + threadIdx.x;
    if (idx >= 4096 * 304) return;
    int combo = idx / 304;
    int c = idx - combo * 304;
    if (c >= HDIM) { etab[idx] = 0; return; }
    int a0 = combo & 15, a1 = (combo >> 4) & 15, a2 = combo >> 8;
    float v = bond_l[a0 * HDIM + c] + bond_l[16 * HDIM + a1 * HDIM + c]
            + bond_l[32 * HDIM + a2 * HDIM + c];
    etab[idx] = f2bf(v);
}

// ---------------------------------------------------------------------------
// Weight swizzle into MFMA B-fragment order.
// Wt1s: [l][nt(40)][kb(10)][lane(64)][8]; Wt2s: [l][nt(20)][kb(20)][lane(64)][8]
// ---------------------------------------------------------------------------
__global__ void prep_w_swz(const float* __restrict__ W1, const float* __restrict__ W2,
                           short* __restrict__ Wt1s, short* __restrict__ Wt2s) {
    int idx = blockIdx.x * blockDim.x + threadIdx.x;
    const int G1 = NLAYERS * 40 * 10 * 64;
    const int G2 = NLAYERS * 20 * 20 * 64;
    if (idx < G1) {
        int l = idx / (40 * 10 * 64);
        int r = idx - l * (40 * 10 * 64);
        int nt = r / (10 * 64);
        int r2 = r - nt * (10 * 64);
        int kb = r2 >> 6;
        int lane = r2 & 63;
        int n = nt * 16 + (lane & 15);
        int k0 = kb * 32 + (lane >> 4) * 8;
        s16x8 o;
#pragma unroll
        for (int j = 0; j < 8; j++) {
            int k = k0 + j;
            float v = (n < H2DIM && k < HDIM) ? W1[((size_t)l * HDIM + k) * H2DIM + n] : 0.f;
            o[j] = f2bf(v);
        }
        *(s16x8*)&Wt1s[(size_t)idx * 8] = o;
    } else if (idx < G1 + G2) {
        int t = idx - G1;
        int l = t / (20 * 20 * 64);
        int r = t - l * (20 * 20 * 64);
        int nt = r / (20 * 64);
        int r2 = r - nt * (20 * 64);
        int kb = r2 >> 6;
        int lane = r2 & 63;
        int n = nt * 16 + (lane & 15);
        int k0 = kb * 32 + (lane >> 4) * 8;
        s16x8 o;
#pragma unroll
        for (int j = 0; j < 8; j++) {
            int k = k0 + j;
            float v = (n < HDIM && k < H2DIM) ? W2[((size_t)l * H2DIM + k) * HDIM + n] : 0.f;
            o[j] = f2bf(v);
        }
        *(s16x8*)&Wt2s[(size_t)t * 8] = o;
    }
}

// ---------------------------------------------------------------------------
// AtomEncoder -> h bf16 (vectorized: one thread per 4 cols)
// ---------------------------------------------------------------------------
__global__ void atom_kernel(const int* __restrict__ x,
                            const float* __restrict__ atom_emb,
                            short* __restrict__ h) {
    int i = blockIdx.x * blockDim.x + threadIdx.x;
    if (i >= N_NODES * 75) return;
    int n = i / 75;
    int c = (i - n * 75) * 4;
    const int* xr = x + n * 9;
    float4 s = {0.f, 0.f, 0.f, 0.f};
#pragma unroll
    for (int f = 0; f < 9; f++) {
        float4 v = *(const float4*)&atom_emb[(size_t)(f * 120 + xr[f]) * HDIM + c];
        s.x += v.x; s.y += v.y; s.z += v.z; s.w += v.w;
    }
    s16x4 o = {f2bf(s.x), f2bf(s.y), f2bf(s.z), f2bf(s.w)};
    *(s16x4*)&h[(size_t)n * HDIM + c] = o;
}

// ---------------------------------------------------------------------------
// Aggregation kernel (unchanged from R6-R8)
// ---------------------------------------------------------------------------
__launch_bounds__(256)
__global__ void agg_kernel(const short* __restrict__ h_in,
                           short* __restrict__ z,
                           const int* __restrict__ offs,
                           const int* __restrict__ sidx,
                           const short* __restrict__ etab,
                           const float* __restrict__ eps, int l) {
    int tid = threadIdx.x;
    int q = tid >> 4;
    int l16 = tid & 15;
    int n = blockIdx.x * 16 + q;
    float e1 = 1.f + eps[l];
    int beg = (n == 0) ? 0 : offs[n - 1];
    int end = offs[n];

    float4 acc[5];
#pragma unroll
    for (int j = 0; j < 5; j++) acc[j] = (float4){0.f, 0.f, 0.f, 0.f};
    bool tail = l16 < 11;
    int ctail = 256 + l16 * 4;

    int e = beg;
    for (; e + 2 <= end; e += 2) {
        int pk0 = sidx[e];
        int pk1 = sidx[e + 1];
        const short* hr0 = h_in + (size_t)(pk0 & 0x3FFFF) * HDIM;
        const short* er0 = etab + (((unsigned)pk0) >> 18) * 304;
        const short* hr1 = h_in + (size_t)(pk1 & 0x3FFFF) * HDIM;
        const short* er1 = etab + (((unsigned)pk1) >> 18) * 304;
        s16x4 hv0[5], ev0[5], hv1[5], ev1[5];
#pragma unroll
        for (int rep = 0; rep < 4; rep++) {
            int c = rep * 64 + l16 * 4;
            hv0[rep] = *(const s16x4*)(hr0 + c);
            ev0[rep] = *(const s16x4*)(er0 + c);
            hv1[rep] = *(const s16x4*)(hr1 + c);
            ev1[rep] = *(const s16x4*)(er1 + c);
        }
        if (tail) {
            hv0[4] = *(const s16x4*)(hr0 + ctail);
            ev0[4] = *(const s16x4*)(er0 + ctail);
            hv1[4] = *(const s16x4*)(hr1 + ctail);
            ev1[4] = *(const s16x4*)(er1 + ctail);
        }
#pragma unroll
        for (int rep = 0; rep < 5; rep++) {
            if (rep == 4 && !tail) continue;
            acc[rep].x += fmaxf(0.f, bf2f(hv0[rep].x) + bf2f(ev0[rep].x))
                        + fmaxf(0.f, bf2f(hv1[rep].x) + bf2f(ev1[rep].x));
            acc[rep].y += fmaxf(0.f, bf2f(hv0[rep].y) + bf2f(ev0[rep].y))
                        + fmaxf(0.f, bf2f(hv1[rep].y) + bf2f(ev1[rep].y));
            acc[rep].z += fmaxf(0.f, bf2f(hv0[rep].z) + bf2f(ev0[rep].z))
                        + fmaxf(0.f, bf2f(hv1[rep].z) + bf2f(ev1[rep].z));
            acc[rep].w += fmaxf(0.f, bf2f(hv0[rep].w) + bf2f(ev0[rep].w))
                        + fmaxf(0.f, bf2f(hv1[rep].w) + bf2f(ev1[rep].w));
        }
    }
    if (e < end) {
        int pk0 = sidx[e];
        const short* hr0 = h_in + (size_t)(pk0 & 0x3FFFF) * HDIM;
        const short* er0 = etab + (((unsigned)pk0) >> 18) * 304;
        s16x4 hv0[5], ev0[5];
#pragma unroll
        for (int rep = 0; rep < 4; rep++) {
            int c = rep * 64 + l16 * 4;
            hv0[rep] = *(const s16x4*)(hr0 + c);
            ev0[rep] = *(const s16x4*)(er0 + c);
        }
        if (tail) {
            hv0[4] = *(const s16x4*)(hr0 + ctail);
            ev0[4] = *(const s16x4*)(er0 + ctail);
        }
#pragma unroll
        for (int rep = 0; rep < 5; rep++) {
            if (rep == 4 && !tail) continue;
            acc[rep].x += fmaxf(0.f, bf2f(hv0[rep].x) + bf2f(ev0[rep].x));
            acc[rep].y += fmaxf(0.f, bf2f(hv0[rep].y) + bf2f(ev0[rep].y));
            acc[rep].z += fmaxf(0.f, bf2f(hv0[rep].z) + bf2f(ev0[rep].z));
            acc[rep].w += fmaxf(0.f, bf2f(hv0[rep].w) + bf2f(ev0[rep].w));
        }
    }

    const short* hn = h_in + (size_t)n * HDIM;
    short* zr = z + (size_t)n * HDIM;
#pragma unroll
    for (int rep = 0; rep < 5; rep++) {
        if (rep == 4 && !tail) continue;
        int c = rep < 4 ? rep * 64 + l16 * 4 : ctail;
        s16x4 hv = *(const s16x4*)(hn + c);
        s16x4 o;
        o.x = f2bf(fmaf(e1, bf2f(hv.x), acc[rep].x));
        o.y = f2bf(fmaf(e1, bf2f(hv.y), acc[rep].y));
        o.z = f2bf(fmaf(e1, bf2f(hv.z), acc[rep].z));
        o.w = f2bf(fmaf(e1, bf2f(hv.w), acc[rep].w));
        *(s16x4*)(zr + c) = o;
    }
}

// ---------------------------------------------------------------------------
// MLP kernel v7: R11 structure (no Zs tile, A direct from global, LDS
// 38400B -> 4 blocks/CU) with the launch-bounds fix: (256,2) keeps VGPR at
// ~120 (R7/R8/R10 evidence) so the 80-VGPR acc2 stays in registers.
// R11's (256,4) forced VGPR=64 -> full accumulator spill (2.15 GB scratch
// FETCH/dispatch). HW occupancy: LDS 160/38.4=4, VGPR 2048/(120*4)=4 blocks.
// ---------------------------------------------------------------------------
#define WBUF_OFF 0
#define WBUF_SHORTS (20 * 64 * 8)              /* 10240 shorts = 20480 B */
#define YS_OFF WBUF_SHORTS                     /* 10240 */
#define YST 136
#define LDS_SHORTS (64 * HDIM)                 /* 19200 shorts = 38400 B */

__launch_bounds__(256, 2)
__global__ void mlp_kernel(const short* __restrict__ zin,
                           short* __restrict__ hout,
                           const short* __restrict__ Wt1,
                           const short* __restrict__ Wt2,
                           const float* __restrict__ b1l,
                           const float* __restrict__ gammal,
                           const float* __restrict__ betal,
                           const float* __restrict__ meanl,
                           const float* __restrict__ varl,
                           const float* __restrict__ b2l) {
    __shared__ short lds[LDS_SHORTS];
    int tid = threadIdx.x;
    int wng = tid >> 6;          // wave = N-group 0..3
    int lane = tid & 63;
    int quad = lane >> 4;
    int l16 = lane & 15;
    int row0 = blockIdx.x * 64;

    f32x4v acc2[4][5];
#pragma unroll
    for (int rt = 0; rt < 4; rt++)
#pragma unroll
        for (int ct = 0; ct < 5; ct++) acc2[rt][ct] = (f32x4v){0.f, 0.f, 0.f, 0.f};

    for (int cc = 0; cc < 5; cc++) {
        // ---------- stage 1: C1[64 x 128] = Z @ W1[:, cc*128..+127] ----------
        f32x4v acc1[4][2];
#pragma unroll
        for (int rt = 0; rt < 4; rt++)
#pragma unroll
            for (int ct = 0; ct < 2; ct++) acc1[rt][ct] = (f32x4v){0.f, 0.f, 0.f, 0.f};

        for (int kbp = 0; kbp < 5; kbp++) {
            __syncthreads();   // prior Wbuf consumers done
            // DMA 16 KB of W1: 16 chunks of 1KB, 4 per wave
#pragma unroll
            for (int j = 0; j < 4; j++) {
                int c = j * 4 + wng;
                int nt_ = c >> 1, kb2 = c & 1;
                const short* src = Wt1 +
                    ((size_t)(((cc * 8 + nt_) * 10 + kbp * 2 + kb2) * 64) + lane) * 8;
                gload_lds16(src, &lds[WBUF_OFF + c * 512]);
            }
            __syncthreads();
#pragma unroll
            for (int kb2 = 0; kb2 < 2; kb2++) {
                int ks = (kbp * 2 + kb2) * 32 + quad * 8;
                s16x8 a[4];
#pragma unroll
                for (int rt = 0; rt < 4; rt++)
                    a[rt] = *(const s16x8*)&zin[(size_t)(row0 + rt * 16 + l16) * HDIM + ks];
#pragma unroll
                for (int ct = 0; ct < 2; ct++) {
                    int c = (wng * 2 + ct) * 2 + kb2;
                    s16x8 b = *(const s16x8*)&lds[WBUF_OFF + c * 512 + lane * 8];
#pragma unroll
                    for (int rt = 0; rt < 4; rt++)
                        acc1[rt][ct] = __builtin_amdgcn_mfma_f32_16x16x32_bf16(a[rt], b, acc1[rt][ct], 0, 0, 0);
                }
            }
        }
        // ---------- epilogue: BN + ReLU -> Ys ----------
#pragma unroll
        for (int ct = 0; ct < 2; ct++) {
            int kc = wng * 32 + ct * 16 + l16;
            int col = cc * 128 + kc;
            bool valid = col < H2DIM;
            float s = 0.f, sh = 0.f;
            if (valid) {
                s = gammal[col] * rsqrtf(varl[col] + 1e-5f);
                sh = betal[col] + (b1l[col] - meanl[col]) * s;
            }
#pragma unroll
            for (int rt = 0; rt < 4; rt++)
#pragma unroll
                for (int rr = 0; rr < 4; rr++) {
                    float v = valid ? fmaxf(0.f, fmaf(acc1[rt][ct][rr], s, sh)) : 0.f;
                    lds[YS_OFF + (rt * 16 + quad * 4 + rr) * YST + kc] = f2bf(v);
                }
        }
        // ---------- stage 2: acc2 += Ys @ W2[cc*128.., :] ----------
#pragma unroll
        for (int kbl = 0; kbl < 4; kbl++) {
            __syncthreads();   // Ys written + Wbuf consumers done
            // DMA 20 KB of W2: 20 chunks of 1KB, 5 per wave
#pragma unroll
            for (int j = 0; j < 5; j++) {
                int c = j * 4 + wng;
                const short* src = Wt2 +
                    ((size_t)((c * 20 + cc * 4 + kbl) * 64) + lane) * 8;
                gload_lds16(src, &lds[WBUF_OFF + c * 512]);
            }
            __syncthreads();
            int ks = kbl * 32 + quad * 8;
            s16x8 a[4];
#pragma unroll
            for (int rt = 0; rt < 4; rt++)
                a[rt] = *(const s16x8*)&lds[YS_OFF + (rt * 16 + l16) * YST + ks];
#pragma unroll
            for (int ct = 0; ct < 5; ct++) {
                int c = wng * 5 + ct;
                s16x8 b = *(const s16x8*)&lds[WBUF_OFF + c * 512 + lane * 8];
#pragma unroll
                for (int rt = 0; rt < 4; rt++)
                    acc2[rt][ct] = __builtin_amdgcn_mfma_f32_16x16x32_bf16(a[rt], b, acc2[rt][ct], 0, 0, 0);
            }
        }
    }
    // ---------- epilogue: h-tile into LDS (stride 300, overlaps Wbuf+Ys:
    // barrier first), then coalesced contiguous copy-out ----------
    __syncthreads();
#pragma unroll
    for (int ct = 0; ct < 5; ct++) {
        int col = wng * 80 + ct * 16 + l16;
        if (col < HDIM) {
            float bb = b2l[col];
#pragma unroll
            for (int rt = 0; rt < 4; rt++)
#pragma unroll
                for (int rr = 0; rr < 4; rr++) {
                    int r = rt * 16 + quad * 4 + rr;
                    lds[r * HDIM + col] = f2bf(acc2[rt][ct][rr] + bb);
                }
        }
    }
    __syncthreads();
    for (int i = tid; i < 64 * 75; i += 256) {
        *(s16x4*)&hout[(size_t)row0 * HDIM + i * 4] = *(const s16x4*)&lds[i * 4];
    }
}

// ---------------------------------------------------------------------------
// Mean pool per graph (batch sorted) + classifier (vectorized)
// ---------------------------------------------------------------------------
__device__ int lower_bound_dev(const int* a, int n, int v) {
    int lo = 0, hi = n;
    while (lo < hi) {
        int mid = (lo + hi) >> 1;
        if (a[mid] < v) lo = mid + 1; else hi = mid;
    }
    return lo;
}

__global__ void pool_kernel(const short* __restrict__ h,
                            const int* __restrict__ batch,
                            const float* __restrict__ cls_W,
                            const float* __restrict__ cls_b,
                            float* __restrict__ out) {
    __shared__ int seg[2];
    __shared__ float r0s[256], r1s[256];
    int g = blockIdx.x;
    int t = threadIdx.x;
    if (t == 0) {
        seg[0] = lower_bound_dev(batch, N_NODES, g);
        seg[1] = lower_bound_dev(batch, N_NODES, g + 1);
    }
    __syncthreads();
    int s = seg[0], e = seg[1];
    float inv = 1.f / fmaxf((float)(e - s), 1.f);
    float p0 = 0.f, p1 = 0.f;
    if (t < 75) {
        int c = t * 4;
        float4 sum = {0.f, 0.f, 0.f, 0.f};
        for (int n = s; n < e; n++) {
            s16x4 v = *(const s16x4*)&h[(size_t)n * HDIM + c];
            sum.x += bf2f(v.x);
            sum.y += bf2f(v.y);
            sum.z += bf2f(v.z);
            sum.w += bf2f(v.w);
        }
        float4 gf = {sum.x * inv, sum.y * inv, sum.z * inv, sum.w * inv};
        *(float4*)&out[2 * N_GRAPHS + (size_t)g * HDIM + c] = gf;
        p0 = gf.x * cls_W[c * 2] + gf.y * cls_W[(c + 1) * 2]
           + gf.z * cls_W[(c + 2) * 2] + gf.w * cls_W[(c + 3) * 2];
        p1 = gf.x * cls_W[c * 2 + 1] + gf.y * cls_W[(c + 1) * 2 + 1]
           + gf.z * cls_W[(c + 2) * 2 + 1] + gf.w * cls_W[(c + 3) * 2 + 1];
    }
    r0s[t] = p0;
    r1s[t] = p1;
    __syncthreads();
    for (int st = 128; st > 0; st >>= 1) {
        if (t < st) { r0s[t] += r0s[t + st]; r1s[t] += r1s[t + st]; }
        __syncthreads();
    }
    if (t == 0) {
        out[g * 2 + 0] = r0s[0] + cls_b[0];
        out[g * 2 + 1] = r1s[0] + cls_b[1];
    }
}

// ---------------------------------------------------------------------------
extern "C" void kernel_launch(void* const* d_in, const int* in_sizes, int n_in,
                              void* d_out, int out_size, void* d_ws, size_t ws_size,
                              hipStream_t stream) {
    const int* x          = (const int*)d_in[0];
    const int* edge_index = (const int*)d_in[1];
    const int* edge_attr  = (const int*)d_in[2];
    const int* batch      = (const int*)d_in[3];
    const float* atom_emb = (const float*)d_in[4];
    const float* bond_emb = (const float*)d_in[5];
    const float* eps      = (const float*)d_in[6];
    const float* W1       = (const float*)d_in[7];
    const float* b1       = (const float*)d_in[8];
    const float* bn_gamma = (const float*)d_in[9];
    const float* bn_beta  = (const float*)d_in[10];
    const float* bn_mean  = (const float*)d_in[11];
    const float* bn_var   = (const float*)d_in[12];
    const float* W2       = (const float*)d_in[13];
    const float* b2       = (const float*)d_in[14];
    const float* cls_W    = (const float*)d_in[15];
    const float* cls_b    = (const float*)d_in[16];
    float* out = (float*)d_out;

    char* base = (char*)d_ws;
    const size_t OFF_HA   = 0;                       // 120,000,000
    const size_t OFF_HB   = 120000000;               // 120,000,000 (z / ping-pong)
    const size_t OFF_WT1  = 240000000;               //   2,048,000
    const size_t OFF_WT2  = 242048000;               //   2,048,000
    const size_t OFF_ETAB = 244096000;               //   2,490,368
    const size_t OFF_SIDX = 246586368;               //   1,600,000
    const size_t OFF_OFFS = 248186368;               //     800,016
    const size_t OFF_BSUM = 248986384;               //         784
    const size_t TOTAL    = 248987168;

    if (ws_size < TOTAL) {
        float mb = (float)(ws_size >> 20);
        diag_kernel<<<(out_size + 255) / 256, 256, 0, stream>>>(out, out_size, mb);
        return;
    }

    short* hA   = (short*)(base + OFF_HA);
    short* hB   = (short*)(base + OFF_HB);
    short* Wt1s = (short*)(base + OFF_WT1);
    short* Wt2s = (short*)(base + OFF_WT2);
    short* etab = (short*)(base + OFF_ETAB);
    int*   sidx = (int*)(base + OFF_SIDX);
    int*   offs = (int*)(base + OFF_OFFS);
    int*   bsum = (int*)(base + OFF_BSUM);

    // ---- edge sort by dst ----
    hipMemsetAsync(offs, 0, SCAN_N * sizeof(int), stream);
    hist_kernel<<<(N_EDGES + 255) / 256, 256, 0, stream>>>(edge_index, offs);
    scan1_kernel<<<196, 256, 0, stream>>>(offs, bsum);
    scan2_kernel<<<1, 256, 0, stream>>>(bsum, 196);
    scan3_kernel<<<(SCAN_N + 255) / 256, 256, 0, stream>>>(offs, bsum);
    scatter_kernel<<<(N_EDGES + 255) / 256, 256, 0, stream>>>(edge_index, edge_attr, offs, sidx);

    // ---- weight swizzle + atom encoder ----
    {
        int total = NLAYERS * 40 * 10 * 64 + NLAYERS * 20 * 20 * 64;
        prep_w_swz<<<(total + 255) / 256, 256, 0, stream>>>(W1, W2, Wt1s, Wt2s);
    }
    atom_kernel<<<(N_NODES * 75 + 255) / 256, 256, 0, stream>>>(x, atom_emb, hA);

    // ---- layers: agg hA->hB(z), mlp hB->hA ----
    for (int l = 0; l < NLAYERS; l++) {
        etab_kernel<<<(4096 * 304 + 255) / 256, 256, 0, stream>>>(
            bond_emb + (size_t)l * 3 * 16 * HDIM, etab);
        agg_kernel<<<N_NODES / 16, 256, 0, stream>>>(
            hA, hB, offs, sidx, etab, eps, l);
        mlp_kernel<<<N_NODES / 64, 256, 0, stream>>>(
            hB, hA,
            Wt1s + (size_t)l * 640 * 320, Wt2s + (size_t)l * 320 * 640,
            b1 + l * H2DIM, bn_gamma + l * H2DIM, bn_beta + l * H2DIM,
            bn_mean + l * H2DIM, bn_var + l * H2DIM, b2 + l * HDIM);
    }

    // ---- pool + classifier ----
    pool_kernel<<<N_GRAPHS, 256, 0, stream>>>(hA, batch, cls_W, cls_b, out);
}

// Round 13
// 2644.030 us; speedup vs baseline: 2.5070x; 1.6900x over previous
//
#include <hip/hip_runtime.h>
#include <hip/hip_bf16.h>

#define N_NODES 200000
#define N_EDGES 400000
#define N_GRAPHS 4096
#define HDIM 300
#define H2DIM 600
#define NLAYERS 5

typedef __hip_bfloat16 bf16;
typedef __attribute__((ext_vector_type(4))) short s16x4;
typedef __attribute__((ext_vector_type(8))) short s16x8;
typedef __attribute__((ext_vector_type(4))) float f32x4v;

__device__ inline short f2bf(float f) {
    __hip_bfloat16 b = __float2bfloat16(f);
    return *(short*)&b;
}
__device__ inline float bf2f(short s) {
    __hip_bfloat16 b = *(__hip_bfloat16*)&s;
    return __bfloat162float(b);
}

// async global->LDS DMA, 16B per lane; LDS dest = wave-uniform base + lane*16
__device__ inline void gload_lds16(const short* g, short* l) {
    __builtin_amdgcn_global_load_lds(
        (const __attribute__((address_space(1))) unsigned int*)g,
        (__attribute__((address_space(3))) unsigned int*)l,
        16, 0, 0);
}

// ---------------------------------------------------------------------------
// Diagnostic (ws too small): report ws_size MB via d_out
// ---------------------------------------------------------------------------
__global__ void diag_kernel(float* __restrict__ out, int n, float val) {
    int i = blockIdx.x * blockDim.x + threadIdx.x;
    if (i < n) out[i] = val;
}

// ---------------------------------------------------------------------------
// Edge sort by dst: histogram -> scan -> scatter.
// ---------------------------------------------------------------------------
__global__ void hist_kernel(const int* __restrict__ edge_index, int* __restrict__ offs) {
    int e = blockIdx.x * blockDim.x + threadIdx.x;
    if (e >= N_EDGES) return;
    atomicAdd(&offs[edge_index[N_EDGES + e]], 1);
}

#define SCAN_N 200001
__global__ void scan1_kernel(int* __restrict__ offs, int* __restrict__ bsum) {
    __shared__ int ls[256];
    int tid = threadIdx.x;
    int base = blockIdx.x * 1024 + tid * 4;
    int v[4];
#pragma unroll
    for (int j = 0; j < 4; j++) v[j] = (base + j < SCAN_N) ? offs[base + j] : 0;
    int t = v[0] + v[1] + v[2] + v[3];
    ls[tid] = t;
    __syncthreads();
    for (int off = 1; off < 256; off <<= 1) {
        int y = (tid >= off) ? ls[tid - off] : 0;
        __syncthreads();
        ls[tid] += y;
        __syncthreads();
    }
    int ex = ls[tid] - t;
#pragma unroll
    for (int j = 0; j < 4; j++) {
        if (base + j < SCAN_N) offs[base + j] = ex;
        ex += v[j];
    }
    if (tid == 255) bsum[blockIdx.x] = ls[255];
}

__global__ void scan2_kernel(int* __restrict__ bsum, int nb) {
    __shared__ int ls[256];
    int tid = threadIdx.x;
    int v = (tid < nb) ? bsum[tid] : 0;
    ls[tid] = v;
    __syncthreads();
    for (int off = 1; off < 256; off <<= 1) {
        int y = (tid >= off) ? ls[tid - off] : 0;
        __syncthreads();
        ls[tid] += y;
        __syncthreads();
    }
    if (tid < nb) bsum[tid] = ls[tid] - v;
}

__global__ void scan3_kernel(int* __restrict__ offs, const int* __restrict__ bsum) {
    int i = blockIdx.x * blockDim.x + threadIdx.x;
    if (i >= SCAN_N) return;
    offs[i] += bsum[i >> 10];
}

__global__ void scatter_kernel(const int* __restrict__ edge_index,
                               const int* __restrict__ edge_attr,
                               int* __restrict__ offs,
                               int* __restrict__ sidx) {
    int e = blockIdx.x * blockDim.x + threadIdx.x;
    if (e >= N_EDGES) return;
    int src = edge_index[e];
    int dst = edge_index[N_EDGES + e];
    int combo = edge_attr[e * 3 + 0] | (edge_attr[e * 3 + 1] << 4) | (edge_attr[e * 3 + 2] << 8);
    int pos = atomicAdd(&offs[dst], 1);
    sidx[pos] = src | (combo << 18);
}

// ---------------------------------------------------------------------------
// Bond-embedding table: etab[combo][c] (stride 304), bf16
// ---------------------------------------------------------------------------
__global__ void etab_kernel(const float* __restrict__ bond_l, short* __restrict__ etab) {
    int idx = blockIdx.x * blockDim.x + threadIdx.x;
    if (idx >= 4096 * 304) return;
    int combo = idx / 304;
    int c = idx - combo * 304;
    if (c >= HDIM) { etab[idx] = 0; return; }
    int a0 = combo & 15, a1 = (combo >> 4) & 15, a2 = combo >> 8;
    float v = bond_l[a0 * HDIM + c] + bond_l[16 * HDIM + a1 * HDIM + c]
            + bond_l[32 * HDIM + a2 * HDIM + c];
    etab[idx] = f2bf(v);
}

// ---------------------------------------------------------------------------
// Weight swizzle into MFMA B-fragment order.
// Wt1s: [l][nt(40)][kb(10)][lane(64)][8]; Wt2s: [l][nt(20)][kb(20)][lane(64)][8]
// ---------------------------------------------------------------------------
__global__ void prep_w_swz(const float* __restrict__ W1, const float* __restrict__ W2,
                           short* __restrict__ Wt1s, short* __restrict__ Wt2s) {
    int idx = blockIdx.x * blockDim.x + threadIdx.x;
    const int G1 = NLAYERS * 40 * 10 * 64;
    const int G2 = NLAYERS * 20 * 20 * 64;
    if (idx < G1) {
        int l = idx / (40 * 10 * 64);
        int r = idx - l * (40 * 10 * 64);
        int nt = r / (10 * 64);
        int r2 = r - nt * (10 * 64);
        int kb = r2 >> 6;
        int lane = r2 & 63;
        int n = nt * 16 + (lane & 15);
        int k0 = kb * 32 + (lane >> 4) * 8;
        s16x8 o;
#pragma unroll
        for (int j = 0; j < 8; j++) {
            int k = k0 + j;
            float v = (n < H2DIM && k < HDIM) ? W1[((size_t)l * HDIM + k) * H2DIM + n] : 0.f;
            o[j] = f2bf(v);
        }
        *(s16x8*)&Wt1s[(size_t)idx * 8] = o;
    } else if (idx < G1 + G2) {
        int t = idx - G1;
        int l = t / (20 * 20 * 64);
        int r = t - l * (20 * 20 * 64);
        int nt = r / (20 * 64);
        int r2 = r - nt * (20 * 64);
        int kb = r2 >> 6;
        int lane = r2 & 63;
        int n = nt * 16 + (lane & 15);
        int k0 = kb * 32 + (lane >> 4) * 8;
        s16x8 o;
#pragma unroll
        for (int j = 0; j < 8; j++) {
            int k = k0 + j;
            float v = (n < HDIM && k < H2DIM) ? W2[((size_t)l * H2DIM + k) * HDIM + n] : 0.f;
            o[j] = f2bf(v);
        }
        *(s16x8*)&Wt2s[(size_t)t * 8] = o;
    }
}

// ---------------------------------------------------------------------------
// AtomEncoder -> h bf16 (vectorized: one thread per 4 cols)
// ---------------------------------------------------------------------------
__global__ void atom_kernel(const int* __restrict__ x,
                            const float* __restrict__ atom_emb,
                            short* __restrict__ h) {
    int i = blockIdx.x * blockDim.x + threadIdx.x;
    if (i >= N_NODES * 75) return;
    int n = i / 75;
    int c = (i - n * 75) * 4;
    const int* xr = x + n * 9;
    float4 s = {0.f, 0.f, 0.f, 0.f};
#pragma unroll
    for (int f = 0; f < 9; f++) {
        float4 v = *(const float4*)&atom_emb[(size_t)(f * 120 + xr[f]) * HDIM + c];
        s.x += v.x; s.y += v.y; s.z += v.z; s.w += v.w;
    }
    s16x4 o = {f2bf(s.x), f2bf(s.y), f2bf(s.z), f2bf(s.w)};
    *(s16x4*)&h[(size_t)n * HDIM + c] = o;
}

// ---------------------------------------------------------------------------
// Aggregation kernel (unchanged from R6-R8)
// ---------------------------------------------------------------------------
__launch_bounds__(256)
__global__ void agg_kernel(const short* __restrict__ h_in,
                           short* __restrict__ z,
                           const int* __restrict__ offs,
                           const int* __restrict__ sidx,
                           const short* __restrict__ etab,
                           const float* __restrict__ eps, int l) {
    int tid = threadIdx.x;
    int q = tid >> 4;
    int l16 = tid & 15;
    int n = blockIdx.x * 16 + q;
    float e1 = 1.f + eps[l];
    int beg = (n == 0) ? 0 : offs[n - 1];
    int end = offs[n];

    float4 acc[5];
#pragma unroll
    for (int j = 0; j < 5; j++) acc[j] = (float4){0.f, 0.f, 0.f, 0.f};
    bool tail = l16 < 11;
    int ctail = 256 + l16 * 4;

    int e = beg;
    for (; e + 2 <= end; e += 2) {
        int pk0 = sidx[e];
        int pk1 = sidx[e + 1];
        const short* hr0 = h_in + (size_t)(pk0 & 0x3FFFF) * HDIM;
        const short* er0 = etab + (((unsigned)pk0) >> 18) * 304;
        const short* hr1 = h_in + (size_t)(pk1 & 0x3FFFF) * HDIM;
        const short* er1 = etab + (((unsigned)pk1) >> 18) * 304;
        s16x4 hv0[5], ev0[5], hv1[5], ev1[5];
#pragma unroll
        for (int rep = 0; rep < 4; rep++) {
            int c = rep * 64 + l16 * 4;
            hv0[rep] = *(const s16x4*)(hr0 + c);
            ev0[rep] = *(const s16x4*)(er0 + c);
            hv1[rep] = *(const s16x4*)(hr1 + c);
            ev1[rep] = *(const s16x4*)(er1 + c);
        }
        if (tail) {
            hv0[4] = *(const s16x4*)(hr0 + ctail);
            ev0[4] = *(const s16x4*)(er0 + ctail);
            hv1[4] = *(const s16x4*)(hr1 + ctail);
            ev1[4] = *(const s16x4*)(er1 + ctail);
        }
#pragma unroll
        for (int rep = 0; rep < 5; rep++) {
            if (rep == 4 && !tail) continue;
            acc[rep].x += fmaxf(0.f, bf2f(hv0[rep].x) + bf2f(ev0[rep].x))
                        + fmaxf(0.f, bf2f(hv1[rep].x) + bf2f(ev1[rep].x));
            acc[rep].y += fmaxf(0.f, bf2f(hv0[rep].y) + bf2f(ev0[rep].y))
                        + fmaxf(0.f, bf2f(hv1[rep].y) + bf2f(ev1[rep].y));
            acc[rep].z += fmaxf(0.f, bf2f(hv0[rep].z) + bf2f(ev0[rep].z))
                        + fmaxf(0.f, bf2f(hv1[rep].z) + bf2f(ev1[rep].z));
            acc[rep].w += fmaxf(0.f, bf2f(hv0[rep].w) + bf2f(ev0[rep].w))
                        + fmaxf(0.f, bf2f(hv1[rep].w) + bf2f(ev1[rep].w));
        }
    }
    if (e < end) {
        int pk0 = sidx[e];
        const short* hr0 = h_in + (size_t)(pk0 & 0x3FFFF) * HDIM;
        const short* er0 = etab + (((unsigned)pk0) >> 18) * 304;
        s16x4 hv0[5], ev0[5];
#pragma unroll
        for (int rep = 0; rep < 4; rep++) {
            int c = rep * 64 + l16 * 4;
            hv0[rep] = *(const s16x4*)(hr0 + c);
            ev0[rep] = *(const s16x4*)(er0 + c);
        }
        if (tail) {
            hv0[4] = *(const s16x4*)(hr0 + ctail);
            ev0[4] = *(const s16x4*)(er0 + ctail);
        }
#pragma unroll
        for (int rep = 0; rep < 5; rep++) {
            if (rep == 4 && !tail) continue;
            acc[rep].x += fmaxf(0.f, bf2f(hv0[rep].x) + bf2f(ev0[rep].x));
            acc[rep].y += fmaxf(0.f, bf2f(hv0[rep].y) + bf2f(ev0[rep].y));
            acc[rep].z += fmaxf(0.f, bf2f(hv0[rep].z) + bf2f(ev0[rep].z));
            acc[rep].w += fmaxf(0.f, bf2f(hv0[rep].w) + bf2f(ev0[rep].w));
        }
    }

    const short* hn = h_in + (size_t)n * HDIM;
    short* zr = z + (size_t)n * HDIM;
#pragma unroll
    for (int rep = 0; rep < 5; rep++) {
        if (rep == 4 && !tail) continue;
        int c = rep < 4 ? rep * 64 + l16 * 4 : ctail;
        s16x4 hv = *(const s16x4*)(hn + c);
        s16x4 o;
        o.x = f2bf(fmaf(e1, bf2f(hv.x), acc[rep].x));
        o.y = f2bf(fmaf(e1, bf2f(hv.y), acc[rep].y));
        o.z = f2bf(fmaf(e1, bf2f(hv.z), acc[rep].z));
        o.w = f2bf(fmaf(e1, bf2f(hv.w), acc[rep].w));
        *(s16x4*)(zr + c) = o;
    }
}

// ---------------------------------------------------------------------------
// MLP kernel v8: R8's exact 2-barrier structure, widened to 128 rows/block
// (512 threads, 8 waves = 2 row-halves x 4 N-groups). Halves the per-block
// W DMA traffic (each block still streams the full 800KB of W, but there are
// half as many blocks) and doubles per-chunk compute vs the same DMA drain.
// LDS: Zs[128][328] 83968B + Wbuf 20480B + Ys[128][136] 34816B = 139264B
// -> 1 block/CU x 8 waves (same waves/CU as R8's 2x4).
// Per-wave register layout identical to R8 (~128 VGPR, no spill).
// ---------------------------------------------------------------------------
#define ZST 328
#define WBUF_OFF (128 * ZST)                   /* 41984 shorts */
#define WBUF_SHORTS (20 * 64 * 8)              /* 10240 shorts = 20480 B */
#define YS_OFF (WBUF_OFF + WBUF_SHORTS)        /* 52224 shorts */
#define YST 136
#define LDS_SHORTS (YS_OFF + 128 * YST)        /* 69632 shorts = 139264 B */

__launch_bounds__(512, 2)
__global__ void mlp_kernel(const short* __restrict__ zin,
                           short* __restrict__ hout,
                           const short* __restrict__ Wt1,
                           const short* __restrict__ Wt2,
                           const float* __restrict__ b1l,
                           const float* __restrict__ gammal,
                           const float* __restrict__ betal,
                           const float* __restrict__ meanl,
                           const float* __restrict__ varl,
                           const float* __restrict__ b2l) {
    __shared__ short lds[LDS_SHORTS];
    int tid = threadIdx.x;
    int w = tid >> 6;            // wave 0..7
    int whalf = w >> 2;          // row half 0..1
    int wng = w & 3;             // N-group 0..3
    int lane = tid & 63;
    int quad = lane >> 4;
    int l16 = lane & 15;
    int row0 = blockIdx.x * 128;
    int rbase = whalf * 64;

    // ---- stage Zs: 128 rows x 328 cols, unguarded (spill cols >=300 are
    // multiplied by zero-padded W rows; reads stay inside d_ws) ----
    for (int i = tid; i < 128 * 82; i += 512) {
        int r = i / 82;
        int p = (i - r * 82) * 4;
        s16x4 v = *(const s16x4*)&zin[(size_t)(row0 + r) * HDIM + p];
        *(s16x4*)&lds[r * ZST + p] = v;
    }
    // (first barrier below publishes Zs)

    f32x4v acc2[4][5];
#pragma unroll
    for (int rt = 0; rt < 4; rt++)
#pragma unroll
        for (int ct = 0; ct < 5; ct++) acc2[rt][ct] = (f32x4v){0.f, 0.f, 0.f, 0.f};

    for (int cc = 0; cc < 5; cc++) {
        // ---------- stage 1: C1[128 x 128] = Z @ W1[:, cc*128..+127] ---------
        f32x4v acc1[4][2];
#pragma unroll
        for (int rt = 0; rt < 4; rt++)
#pragma unroll
            for (int ct = 0; ct < 2; ct++) acc1[rt][ct] = (f32x4v){0.f, 0.f, 0.f, 0.f};

        for (int kbp = 0; kbp < 5; kbp++) {
            __syncthreads();   // prior Wbuf consumers done (publishes Zs 1st)
            // DMA 16 KB of W1: 16 chunks of 1KB, 2 per wave
#pragma unroll
            for (int j = 0; j < 2; j++) {
                int c = j * 8 + w;
                int nt_ = c >> 1, kb2 = c & 1;
                const short* src = Wt1 +
                    ((size_t)(((cc * 8 + nt_) * 10 + kbp * 2 + kb2) * 64) + lane) * 8;
                gload_lds16(src, &lds[WBUF_OFF + c * 512]);
            }
            __syncthreads();
#pragma unroll
            for (int kb2 = 0; kb2 < 2; kb2++) {
                int ks = (kbp * 2 + kb2) * 32 + quad * 8;
                s16x8 a[4];
#pragma unroll
                for (int rt = 0; rt < 4; rt++)
                    a[rt] = *(const s16x8*)&lds[(rbase + rt * 16 + l16) * ZST + ks];
#pragma unroll
                for (int ct = 0; ct < 2; ct++) {
                    int c = (wng * 2 + ct) * 2 + kb2;
                    s16x8 b = *(const s16x8*)&lds[WBUF_OFF + c * 512 + lane * 8];
#pragma unroll
                    for (int rt = 0; rt < 4; rt++)
                        acc1[rt][ct] = __builtin_amdgcn_mfma_f32_16x16x32_bf16(a[rt], b, acc1[rt][ct], 0, 0, 0);
                }
            }
        }
        // ---------- epilogue: BN + ReLU -> Ys ----------
#pragma unroll
        for (int ct = 0; ct < 2; ct++) {
            int kc = wng * 32 + ct * 16 + l16;
            int col = cc * 128 + kc;
            bool valid = col < H2DIM;
            float s = 0.f, sh = 0.f;
            if (valid) {
                s = gammal[col] * rsqrtf(varl[col] + 1e-5f);
                sh = betal[col] + (b1l[col] - meanl[col]) * s;
            }
#pragma unroll
            for (int rt = 0; rt < 4; rt++)
#pragma unroll
                for (int rr = 0; rr < 4; rr++) {
                    float v = valid ? fmaxf(0.f, fmaf(acc1[rt][ct][rr], s, sh)) : 0.f;
                    lds[YS_OFF + (rbase + rt * 16 + quad * 4 + rr) * YST + kc] = f2bf(v);
                }
        }
        // ---------- stage 2: acc2 += Ys @ W2[cc*128.., :] ----------
#pragma unroll
        for (int kbl = 0; kbl < 4; kbl++) {
            __syncthreads();   // Ys written + Wbuf consumers done
            // DMA 20 KB of W2: 20 chunks of 1KB, <=3 per wave
#pragma unroll
            for (int j = 0; j < 3; j++) {
                int c = j * 8 + w;
                if (c < 20) {
                    const short* src = Wt2 +
                        ((size_t)((c * 20 + cc * 4 + kbl) * 64) + lane) * 8;
                    gload_lds16(src, &lds[WBUF_OFF + c * 512]);
                }
            }
            __syncthreads();
            int ks = kbl * 32 + quad * 8;
            s16x8 a[4];
#pragma unroll
            for (int rt = 0; rt < 4; rt++)
                a[rt] = *(const s16x8*)&lds[YS_OFF + (rbase + rt * 16 + l16) * YST + ks];
#pragma unroll
            for (int ct = 0; ct < 5; ct++) {
                int c = wng * 5 + ct;
                s16x8 b = *(const s16x8*)&lds[WBUF_OFF + c * 512 + lane * 8];
#pragma unroll
                for (int rt = 0; rt < 4; rt++)
                    acc2[rt][ct] = __builtin_amdgcn_mfma_f32_16x16x32_bf16(a[rt], b, acc2[rt][ct], 0, 0, 0);
            }
        }
    }
    // ---------- epilogue: h-tile into LDS (stride 300, reuses Zs region),
    // then coalesced contiguous copy-out with last-block row guard ----------
    __syncthreads();
#pragma unroll
    for (int ct = 0; ct < 5; ct++) {
        int col = wng * 80 + ct * 16 + l16;
        if (col < HDIM) {
            float bb = b2l[col];
#pragma unroll
            for (int rt = 0; rt < 4; rt++)
#pragma unroll
                for (int rr = 0; rr < 4; rr++) {
                    int r = rbase + rt * 16 + quad * 4 + rr;
                    lds[r * HDIM + col] = f2bf(acc2[rt][ct][rr] + bb);
                }
        }
    }
    __syncthreads();
    int nrows = N_NODES - row0;
    if (nrows > 128) nrows = 128;
    int cnt = nrows * 75;
    for (int i = tid; i < cnt; i += 512) {
        *(s16x4*)&hout[(size_t)row0 * HDIM + i * 4] = *(const s16x4*)&lds[i * 4];
    }
}

// ---------------------------------------------------------------------------
// Mean pool per graph (batch sorted) + classifier (vectorized)
// ---------------------------------------------------------------------------
__device__ int lower_bound_dev(const int* a, int n, int v) {
    int lo = 0, hi = n;
    while (lo < hi) {
        int mid = (lo + hi) >> 1;
        if (a[mid] < v) lo = mid + 1; else hi = mid;
    }
    return lo;
}

__global__ void pool_kernel(const short* __restrict__ h,
                            const int* __restrict__ batch,
                            const float* __restrict__ cls_W,
                            const float* __restrict__ cls_b,
                            float* __restrict__ out) {
    __shared__ int seg[2];
    __shared__ float r0s[256], r1s[256];
    int g = blockIdx.x;
    int t = threadIdx.x;
    if (t == 0) {
        seg[0] = lower_bound_dev(batch, N_NODES, g);
        seg[1] = lower_bound_dev(batch, N_NODES, g + 1);
    }
    __syncthreads();
    int s = seg[0], e = seg[1];
    float inv = 1.f / fmaxf((float)(e - s), 1.f);
    float p0 = 0.f, p1 = 0.f;
    if (t < 75) {
        int c = t * 4;
        float4 sum = {0.f, 0.f, 0.f, 0.f};
        for (int n = s; n < e; n++) {
            s16x4 v = *(const s16x4*)&h[(size_t)n * HDIM + c];
            sum.x += bf2f(v.x);
            sum.y += bf2f(v.y);
            sum.z += bf2f(v.z);
            sum.w += bf2f(v.w);
        }
        float4 gf = {sum.x * inv, sum.y * inv, sum.z * inv, sum.w * inv};
        *(float4*)&out[2 * N_GRAPHS + (size_t)g * HDIM + c] = gf;
        p0 = gf.x * cls_W[c * 2] + gf.y * cls_W[(c + 1) * 2]
           + gf.z * cls_W[(c + 2) * 2] + gf.w * cls_W[(c + 3) * 2];
        p1 = gf.x * cls_W[c * 2 + 1] + gf.y * cls_W[(c + 1) * 2 + 1]
           + gf.z * cls_W[(c + 2) * 2 + 1] + gf.w * cls_W[(c + 3) * 2 + 1];
    }
    r0s[t] = p0;
    r1s[t] = p1;
    __syncthreads();
    for (int st = 128; st > 0; st >>= 1) {
        if (t < st) { r0s[t] += r0s[t + st]; r1s[t] += r1s[t + st]; }
        __syncthreads();
    }
    if (t == 0) {
        out[g * 2 + 0] = r0s[0] + cls_b[0];
        out[g * 2 + 1] = r1s[0] + cls_b[1];
    }
}

// ---------------------------------------------------------------------------
extern "C" void kernel_launch(void* const* d_in, const int* in_sizes, int n_in,
                              void* d_out, int out_size, void* d_ws, size_t ws_size,
                              hipStream_t stream) {
    const int* x          = (const int*)d_in[0];
    const int* edge_index = (const int*)d_in[1];
    const int* edge_attr  = (const int*)d_in[2];
    const int* batch      = (const int*)d_in[3];
    const float* atom_emb = (const float*)d_in[4];
    const float* bond_emb = (const float*)d_in[5];
    const float* eps      = (const float*)d_in[6];
    const float* W1       = (const float*)d_in[7];
    const float* b1       = (const float*)d_in[8];
    const float* bn_gamma = (const float*)d_in[9];
    const float* bn_beta  = (const float*)d_in[10];
    const float* bn_mean  = (const float*)d_in[11];
    const float* bn_var   = (const float*)d_in[12];
    const float* W2       = (const float*)d_in[13];
    const float* b2       = (const float*)d_in[14];
    const float* cls_W    = (const float*)d_in[15];
    const float* cls_b    = (const float*)d_in[16];
    float* out = (float*)d_out;

    char* base = (char*)d_ws;
    const size_t OFF_HA   = 0;                       // 120,000,000
    const size_t OFF_HB   = 120000000;               // 120,000,000 (z / ping-pong)
    const size_t OFF_WT1  = 240000000;               //   2,048,000
    const size_t OFF_WT2  = 242048000;               //   2,048,000
    const size_t OFF_ETAB = 244096000;               //   2,490,368
    const size_t OFF_SIDX = 246586368;               //   1,600,000
    const size_t OFF_OFFS = 248186368;               //     800,016
    const size_t OFF_BSUM = 248986384;               //         784
    const size_t TOTAL    = 248987168;

    if (ws_size < TOTAL) {
        float mb = (float)(ws_size >> 20);
        diag_kernel<<<(out_size + 255) / 256, 256, 0, stream>>>(out, out_size, mb);
        return;
    }

    short* hA   = (short*)(base + OFF_HA);
    short* hB   = (short*)(base + OFF_HB);
    short* Wt1s = (short*)(base + OFF_WT1);
    short* Wt2s = (short*)(base + OFF_WT2);
    short* etab = (short*)(base + OFF_ETAB);
    int*   sidx = (int*)(base + OFF_SIDX);
    int*   offs = (int*)(base + OFF_OFFS);
    int*   bsum = (int*)(base + OFF_BSUM);

    // ---- edge sort by dst ----
    hipMemsetAsync(offs, 0, SCAN_N * sizeof(int), stream);
    hist_kernel<<<(N_EDGES + 255) / 256, 256, 0, stream>>>(edge_index, offs);
    scan1_kernel<<<196, 256, 0, stream>>>(offs, bsum);
    scan2_kernel<<<1, 256, 0, stream>>>(bsum, 196);
    scan3_kernel<<<(SCAN_N + 255) / 256, 256, 0, stream>>>(offs, bsum);
    scatter_kernel<<<(N_EDGES + 255) / 256, 256, 0, stream>>>(edge_index, edge_attr, offs, sidx);

    // ---- weight swizzle + atom encoder ----
    {
        int total = NLAYERS * 40 * 10 * 64 + NLAYERS * 20 * 20 * 64;
        prep_w_swz<<<(total + 255) / 256, 256, 0, stream>>>(W1, W2, Wt1s, Wt2s);
    }
    atom_kernel<<<(N_NODES * 75 + 255) / 256, 256, 0, stream>>>(x, atom_emb, hA);

    // ---- layers: agg hA->hB(z), mlp hB->hA ----
    for (int l = 0; l < NLAYERS; l++) {
        etab_kernel<<<(4096 * 304 + 255) / 256, 256, 0, stream>>>(
            bond_emb + (size_t)l * 3 * 16 * HDIM, etab);
        agg_kernel<<<N_NODES / 16, 256, 0, stream>>>(
            hA, hB, offs, sidx, etab, eps, l);
        mlp_kernel<<<(N_NODES + 127) / 128, 512, 0, stream>>>(
            hB, hA,
            Wt1s + (size_t)l * 640 * 320, Wt2s + (size_t)l * 320 * 640,
            b1 + l * H2DIM, bn_gamma + l * H2DIM, bn_beta + l * H2DIM,
            bn_mean + l * H2DIM, bn_var + l * H2DIM, b2 + l * HDIM);
    }

    // ---- pool + classifier ----
    pool_kernel<<<N_GRAPHS, 256, 0, stream>>>(hA, batch, cls_W, cls_b, out);
}